// Round 15
// baseline (341.481 us; speedup 1.0000x reference)
//
#include <hip/hip_runtime.h>
#include <cfloat>

#define B_ 32
#define N_ 4096
#define C_ 768
#define T_ 1000
#define K_ 20

#define PHC 32            // floats per c-phase (one MFMA K=32 step)
#define NPH (C_/PHC)      // 24 phases
#define SPP 4             // phases per super-phase (512B row bursts)
#define NSP (NPH/SPP)     // 6 super-phases
#define GAP_TH 1e-4f
#define MAXF 16384

typedef float f32x4 __attribute__((ext_vector_type(4)));
typedef int   i32x4 __attribute__((ext_vector_type(4)));
typedef short s16x8 __attribute__((ext_vector_type(8)));   // 8 bf16 (4 VGPR)

__device__ __forceinline__ unsigned short bf_rne(float x) {
    unsigned u = __float_as_uint(x);
    return (unsigned short)((u + 0x7fffu + ((u >> 16) & 1u)) >> 16);
}

// ---------------- K1a: vg_logit in fp64 (+ zero counters) ----------------
__global__ __launch_bounds__(256) void k1_logits(const float* __restrict__ g_feat,
                                                 const float* __restrict__ text,
                                                 double* __restrict__ logits,
                                                 int* __restrict__ cnt,
                                                 int* __restrict__ flagcnt) {
    int b = blockIdx.x;
    int wid = threadIdx.x >> 6, lane = threadIdx.x & 63;
    int t = blockIdx.y * 4 + wid;           // grid.y = 250 -> t in [0,1000)
    if (b == 0 && blockIdx.y == 0) {
        for (int i = threadIdx.x; i < B_ * K_; i += 256) cnt[i] = 0;
        if (threadIdx.x == 0) flagcnt[0] = 0;
    }
    const float* g = g_feat + b * C_;
    const float* e = text + t * C_;
    double s = 0.0;
    #pragma unroll
    for (int j = 0; j < 12; ++j) {
        int c = lane + 64 * j;
        s += (double)g[c] * (double)e[c];
    }
    #pragma unroll
    for (int m = 32; m; m >>= 1) s += __shfl_xor(s, m);
    if (lane == 0) logits[b * T_ + t] = s;
}

// ---------------- K1b: top-20 + gather + A-fragment-ordered bf16 hi/lo pack ----------------
__global__ __launch_bounds__(256) void k1b_topk(const double* __restrict__ logits,
                                                const float* __restrict__ text,
                                                float* __restrict__ agg,
                                                unsigned short* __restrict__ Epk) {
    __shared__ unsigned short hiL[32 * C_];   // 48 KB
    __shared__ unsigned short loL[32 * C_];   // 48 KB
    __shared__ int ssel[K_];
    int b = blockIdx.x, tid = threadIdx.x, lane = tid & 63;
    if (tid < 64) {
        double v[16];
        #pragma unroll
        for (int j = 0; j < 16; ++j) {
            int t = lane + 64 * j;
            v[j] = (t < T_) ? logits[b * T_ + t] : -DBL_MAX;
        }
        for (int it = 0; it < K_; ++it) {
            double bv = -DBL_MAX; int bi = 0x7fffffff;
            #pragma unroll
            for (int j = 0; j < 16; ++j) {
                int t = lane + 64 * j;
                if (v[j] > bv) { bv = v[j]; bi = t; }
            }
            #pragma unroll
            for (int m = 32; m; m >>= 1) {
                double ov = __shfl_xor(bv, m); int oi = __shfl_xor(bi, m);
                if (ov > bv || (ov == bv && oi < bi)) { bv = ov; bi = oi; }
            }
            if (lane == 0) ssel[it] = bi;
            #pragma unroll
            for (int j = 0; j < 16; ++j) {
                int t = lane + 64 * j;
                if (t == bi) v[j] = -DBL_MAX;
            }
        }
    }
    __syncthreads();
    for (int i = tid; i < 32 * C_; i += 256) {
        int r = i / C_, c = i - r * C_;
        float v = (r < K_) ? text[ssel[r] * C_ + c] : 0.f;
        if (r < K_) agg[b * K_ * C_ + i] = v;
        unsigned u = __float_as_uint(v);
        float fh = __uint_as_float(u & 0xffff0000u);
        hiL[i] = (unsigned short)(u >> 16);
        loL[i] = bf_rne(v - fh);
    }
    __syncthreads();
    for (int i = tid; i < 24 * 256; i += 256) {
        int p = i >> 8, r = i & 255, f = r >> 6, ln = r & 63;
        int row = (f & 1) * 16 + (ln & 15);
        int col = p * 32 + (ln >> 4) * 8;
        const unsigned short* src = ((f < 2) ? hiL : loL) + row * C_ + col;
        *(s16x8*)(Epk + ((size_t)b * 6144 + i) * 8) = *(const s16x8*)src;
    }
}

// ---------------- K2 (PROBE x2): LDS-free MFMA argmax, self-duplicating ----------------
// rep0: full identical instruction stream against shifted addresses (pixel tile
// XOR 128 within batch; Epk batch b^1) -- no CSE, results kept alive via asm.
// rep1: the real computation. k2 duration ~doubles -> crosses the ~230us fill
// threshold and becomes visible in rocprof top-5 WITH its counters.
__global__ __launch_bounds__(256, 4) void k2_argmax(const float* __restrict__ feat,
                                                    const unsigned short* __restrict__ Epk,
                                                    int* __restrict__ kidx,
                                                    int* __restrict__ cnt,
                                                    int* __restrict__ flagcnt,
                                                    int* __restrict__ flaglist) {
    __shared__ int scnt[K_];
    int tid = threadIdx.x, wid = tid >> 6, lane = tid & 63;
    if (tid < K_) scnt[tid] = 0;
    __syncthreads();

    int gw = blockIdx.x * 4 + wid;           // global wave 0..8191
    int b  = gw >> 8;                        // 256 waves per batch
    int n0 = (gw & 255) * 16;                // pixel base within batch
    int n0a = ((gw & 255) ^ 128) * 16;       // probe-rep pixel base (same batch)
    int prow = lane & 15;                    // my pixel within the tile
    int g    = lane >> 4;                    // my k-group (0..3)
    const float* fp1 = feat + ((size_t)b * N_ + n0  + prow) * C_ + g * 8;
    const float* fpa = feat + ((size_t)b * N_ + n0a + prow) * C_ + g * 8;
    const unsigned short* Eb1 = Epk + (size_t)b * 6144 * 8;
    const unsigned short* Eba = Epk + (size_t)(b ^ 1) * 6144 * 8;

    f32x4 fA[2 * SPP], fB[2 * SPP];
    s16x8 Ah0, Ah1, Al0, Al1;
    auto CVT = [&](f32x4 a, f32x4 c, s16x8& H, s16x8& L) {
        float x[8] = { a.x, a.y, a.z, a.w, c.x, c.y, c.z, c.w };
        unsigned hu[8], lu[8];
        #pragma unroll
        for (int j = 0; j < 8; ++j) {
            unsigned u = __float_as_uint(x[j]);
            hu[j] = u >> 16;
            lu[j] = bf_rne(x[j] - __uint_as_float(u & 0xffff0000u));
        }
        i32x4 hv = { (int)(hu[0] | (hu[1] << 16)), (int)(hu[2] | (hu[3] << 16)),
                     (int)(hu[4] | (hu[5] << 16)), (int)(hu[6] | (hu[7] << 16)) };
        i32x4 lv = { (int)(lu[0] | (lu[1] << 16)), (int)(lu[2] | (lu[3] << 16)),
                     (int)(lu[4] | (lu[5] << 16)), (int)(lu[6] | (lu[7] << 16)) };
        H = __builtin_bit_cast(s16x8, hv);
        L = __builtin_bit_cast(s16x8, lv);
    };

    f32x4 acc0, acc1;
    #pragma unroll 1
    for (int rep = 0; rep < 2; ++rep) {
        const float* fp0 = (rep == 0) ? fpa : fp1;
        const unsigned short* Eb = (rep == 0) ? Eba : Eb1;
        acc0 = (f32x4)0.f; acc1 = (f32x4)0.f;

        auto LOADSP = [&](int sp, f32x4* fr) {
            #pragma unroll
            for (int q = 0; q < SPP; ++q) {
                fr[2 * q]     = *(const f32x4*)(fp0 + (sp * SPP + q) * PHC);
                fr[2 * q + 1] = *(const f32x4*)(fp0 + (sp * SPP + q) * PHC + 4);
            }
        };
        auto LOADA = [&](int p) {
            const s16x8* ap = (const s16x8*)(Eb + (size_t)p * 256 * 8);
            Ah0 = ap[lane]; Ah1 = ap[64 + lane];
            Al0 = ap[128 + lane]; Al1 = ap[192 + lane];
        };

        LOADSP(0, fA);
        #pragma unroll 1
        for (int sp = 0; sp < NSP; ++sp) {
            f32x4* cur = (sp & 1) ? fB : fA;
            f32x4* nxt = (sp & 1) ? fA : fB;
            if (sp + 1 < NSP) LOADSP(sp + 1, nxt);
            #pragma unroll
            for (int q = 0; q < SPP; ++q) {
                LOADA(sp * SPP + q);
                s16x8 Bh, Bl;
                CVT(cur[2 * q], cur[2 * q + 1], Bh, Bl);
                acc0 = __builtin_amdgcn_mfma_f32_16x16x32_bf16(Ah0, Bh, acc0, 0, 0, 0);
                acc1 = __builtin_amdgcn_mfma_f32_16x16x32_bf16(Ah1, Bh, acc1, 0, 0, 0);
                acc0 = __builtin_amdgcn_mfma_f32_16x16x32_bf16(Ah0, Bl, acc0, 0, 0, 0);
                acc1 = __builtin_amdgcn_mfma_f32_16x16x32_bf16(Ah1, Bl, acc1, 0, 0, 0);
                acc0 = __builtin_amdgcn_mfma_f32_16x16x32_bf16(Al0, Bh, acc0, 0, 0, 0);
                acc1 = __builtin_amdgcn_mfma_f32_16x16x32_bf16(Al1, Bh, acc1, 0, 0, 0);
            }
        }
        if (rep == 0) {   // keep probe results live (rule #17: no DCE)
            asm volatile("" :: "v"(acc0.x), "v"(acc0.y), "v"(acc0.z), "v"(acc0.w),
                             "v"(acc1.x), "v"(acc1.y), "v"(acc1.z), "v"(acc1.w));
        }
    }

    // epilogue: top-2 over k (C/D: col=lane&15=px, row-class=(lane>>4)*4+reg)
    int kb = g * 4;
    float m1 = acc0[0]; int i1 = kb; float m2 = -FLT_MAX;
    #pragma unroll
    for (int r = 1; r < 4; ++r) {
        float v = acc0[r];
        if (v > m1) { m2 = m1; m1 = v; i1 = kb + r; }
        else if (v > m2) m2 = v;
    }
    if (g == 0) {                            // k-tile 1: only classes 16..19 valid
        #pragma unroll
        for (int r = 0; r < 4; ++r) {
            float v = acc1[r];
            if (v > m1) { m2 = m1; m1 = v; i1 = 16 + r; }
            else if (v > m2) m2 = v;
        }
    }
    #pragma unroll
    for (int s = 16; s < 64; s <<= 1) {
        float om1 = __shfl_xor(m1, s); int oi1 = __shfl_xor(i1, s);
        float om2 = __shfl_xor(m2, s);
        if (om1 > m1 || (om1 == m1 && oi1 < i1)) { m2 = fmaxf(m1, om2); m1 = om1; i1 = oi1; }
        else { m2 = fmaxf(m2, om1); }
    }
    if (lane < 16) {
        int n = n0 + lane;
        kidx[b * N_ + n] = i1;
        atomicAdd(&scnt[i1], 1);
        if (m1 - m2 < GAP_TH) {
            int pos = atomicAdd(flagcnt, 1);
            if (pos < MAXF) flaglist[pos] = b * N_ + n;
        }
    }
    __syncthreads();
    if (tid < K_) atomicAdd(&cnt[b * K_ + tid], scnt[tid]);
}

// ---------------- K2.5: fp64 re-decision for knife-edge pixels ----------------
__global__ __launch_bounds__(256) void k25_refine(const float* __restrict__ feat,
                                                  const float* __restrict__ agg,
                                                  int* __restrict__ kidx,
                                                  int* __restrict__ cnt,
                                                  const int* __restrict__ flagcnt,
                                                  const int* __restrict__ flaglist) {
    int wid = threadIdx.x >> 6, lane = threadIdx.x & 63;
    int wg = blockIdx.x * 4 + wid;
    int nf = flagcnt[0]; if (nf > MAXF) nf = MAXF;
    for (int e = wg; e < nf; e += gridDim.x * 4) {
        int pix = flaglist[e];
        int b = pix >> 12;
        const float* fr = feat + (size_t)pix * C_;
        const float* ebase = agg + b * K_ * C_;
        double fd[12];
        #pragma unroll
        for (int j = 0; j < 12; ++j) fd[j] = (double)fr[lane + 64 * j];
        double best = -DBL_MAX; int bi = 0;
        for (int k = 0; k < K_; ++k) {
            const float* er = ebase + k * C_;
            double s = 0.0;
            #pragma unroll
            for (int j = 0; j < 12; ++j) s += fd[j] * (double)er[lane + 64 * j];
            #pragma unroll
            for (int m = 32; m; m >>= 1) s += __shfl_xor(s, m);
            if (s > best) { best = s; bi = k; }
        }
        if (lane == 0) {
            int old = kidx[pix];
            if (old != bi) {
                kidx[pix] = bi;
                atomicSub(&cnt[b * K_ + old], 1);
                atomicAdd(&cnt[b * K_ + bi], 1);
            }
        }
    }
}

// ---------------- K3s: pre-scale agg rows by 1/(cnt+1) ----------------
__global__ __launch_bounds__(256) void k3s_scale(const float* __restrict__ agg,
                                                 const int* __restrict__ cnt,
                                                 float* __restrict__ sagg) {
    __shared__ float sc[K_];
    int b = blockIdx.x, tid = threadIdx.x;
    if (tid < K_) sc[tid] = 1.0f / ((float)cnt[b * K_ + tid] + 1.0f);  // IEEE div, matches ref
    __syncthreads();
    const f32x4* a4 = (const f32x4*)(agg + (size_t)b * K_ * C_);
    f32x4* s4 = (f32x4*)(sagg + (size_t)b * K_ * C_);
    #pragma unroll 1
    for (int i = tid; i < K_ * (C_ / 4); i += 256) {
        int k = i / (C_ / 4);
        s4[i] = a4[i] * sc[k];
    }
}

// ---------------- K4: gather+store only (8 px/wave, 2-deep pipeline) ----------------
__global__ __launch_bounds__(256) void k4_out(const float* __restrict__ sagg,
                                              const int* __restrict__ kidx,
                                              float* __restrict__ out) {
    int wid = threadIdx.x >> 6, lane = threadIdx.x & 63;
    int wg = blockIdx.x * 4 + wid;          // 16384 waves, 8 px each
    int base = wg * 8;
    int b = base >> 12;                     // wave-uniform (8 | 4096)
    int kk[8];
    #pragma unroll
    for (int i = 0; i < 8; ++i) kk[i] = kidx[base + i];
    const f32x4* sagg4 = (const f32x4*)sagg;
    f32x4* out4 = (f32x4*)out;

    f32x4 va0, va1, va2, vb0, vb1, vb2;
    {
        const f32x4* a4 = sagg4 + (size_t)(b * K_ + kk[0]) * (C_ / 4);
        va0 = a4[lane]; va1 = a4[lane + 64]; va2 = a4[lane + 128];
    }
    #pragma unroll
    for (int i = 0; i < 8; ++i) {
        if (i + 1 < 8) {
            const f32x4* a4 = sagg4 + (size_t)(b * K_ + kk[i + 1]) * (C_ / 4);
            vb0 = a4[lane]; vb1 = a4[lane + 64]; vb2 = a4[lane + 128];
        }
        f32x4* o4 = out4 + (size_t)(base + i) * (C_ / 4);
        o4[lane] = va0; o4[lane + 64] = va1; o4[lane + 128] = va2;
        va0 = vb0; va1 = vb1; va2 = vb2;
    }
}

extern "C" void kernel_launch(void* const* d_in, const int* in_sizes, int n_in,
                              void* d_out, int out_size, void* d_ws, size_t ws_size,
                              hipStream_t stream) {
    const float* g_feat = (const float*)d_in[0];
    const float* feat   = (const float*)d_in[1];
    // d_in[2] = tau: positive scale, numerically irrelevant (attn == y_hard exactly)
    const float* text   = (const float*)d_in[3];
    float* out = (float*)d_out;

    char* ws = (char*)d_ws;
    double* logits        = (double*)(ws + 0);         // 256000 B
    float*  agg           = (float*) (ws + 262144);    // 1966080 B
    int*    cnt           = (int*)   (ws + 2230784);   // 2560 B
    int*    flagc         = (int*)   (ws + 2233344);   // 64 B
    int*    flagl         = (int*)   (ws + 2233408);   // 65536 B
    int*    kidx          = (int*)   (ws + 2301504);   // 524288 B
    unsigned short* Epk   = (unsigned short*)(ws + 2825792);  // 3145728 B
    float*  sagg          = (float*) (ws + 5971520);   // 1966080 B

    k1_logits<<<dim3(32, 250), 256, 0, stream>>>(g_feat, text, logits, cnt, flagc);
    k1b_topk<<<32, 256, 0, stream>>>(logits, text, agg, Epk);
    k2_argmax<<<2048, 256, 0, stream>>>(feat, Epk, kidx, cnt, flagc, flagl);
    k25_refine<<<1024, 256, 0, stream>>>(feat, agg, kidx, cnt, flagc, flagl);
    k3s_scale<<<32, 256, 0, stream>>>(agg, cnt, sagg);
    k4_out<<<4096, 256, 0, stream>>>(sagg, kidx, out);
}

// Round 16
// 274.723 us; speedup vs baseline: 1.2430x; 1.2430x over previous
//
#include <hip/hip_runtime.h>
#include <cfloat>

#define B_ 32
#define N_ 4096
#define C_ 768
#define T_ 1000
#define K_ 20

#define PHC 32            // floats per c-phase (one MFMA K=32 step)
#define NPH (C_/PHC)      // 24 phases
#define ROWF 784          // padded row stride in floats (3136 B)
#define GAP_TH 1e-4f
#define MAXF 16384

typedef float f32x4 __attribute__((ext_vector_type(4)));
typedef int   i32x4 __attribute__((ext_vector_type(4)));
typedef short s16x8 __attribute__((ext_vector_type(8)));   // 8 bf16 (4 VGPR)

__device__ __forceinline__ unsigned short bf_rne(float x) {
    unsigned u = __float_as_uint(x);
    return (unsigned short)((u + 0x7fffu + ((u >> 16) & 1u)) >> 16);
}

// ---------------- K1a: vg_logit in fp64 (+ zero counters) ----------------
__global__ __launch_bounds__(256) void k1_logits(const float* __restrict__ g_feat,
                                                 const float* __restrict__ text,
                                                 double* __restrict__ logits,
                                                 int* __restrict__ cnt,
                                                 int* __restrict__ flagcnt) {
    int b = blockIdx.x;
    int wid = threadIdx.x >> 6, lane = threadIdx.x & 63;
    int t = blockIdx.y * 4 + wid;           // grid.y = 250 -> t in [0,1000)
    if (b == 0 && blockIdx.y == 0) {
        for (int i = threadIdx.x; i < B_ * K_; i += 256) cnt[i] = 0;
        if (threadIdx.x == 0) flagcnt[0] = 0;
    }
    const float* g = g_feat + b * C_;
    const float* e = text + t * C_;
    double s = 0.0;
    #pragma unroll
    for (int j = 0; j < 12; ++j) {
        int c = lane + 64 * j;
        s += (double)g[c] * (double)e[c];
    }
    #pragma unroll
    for (int m = 32; m; m >>= 1) s += __shfl_xor(s, m);
    if (lane == 0) logits[b * T_ + t] = s;
}

// ---------------- K1b: top-20 + gather + A-fragment-ordered bf16 hi/lo pack ----------------
__global__ __launch_bounds__(256) void k1b_topk(const double* __restrict__ logits,
                                                const float* __restrict__ text,
                                                float* __restrict__ agg,
                                                unsigned short* __restrict__ Epk) {
    __shared__ unsigned short hiL[32 * C_];   // 48 KB
    __shared__ unsigned short loL[32 * C_];   // 48 KB
    __shared__ int ssel[K_];
    int b = blockIdx.x, tid = threadIdx.x, lane = tid & 63;
    if (tid < 64) {
        double v[16];
        #pragma unroll
        for (int j = 0; j < 16; ++j) {
            int t = lane + 64 * j;
            v[j] = (t < T_) ? logits[b * T_ + t] : -DBL_MAX;
        }
        for (int it = 0; it < K_; ++it) {
            double bv = -DBL_MAX; int bi = 0x7fffffff;
            #pragma unroll
            for (int j = 0; j < 16; ++j) {
                int t = lane + 64 * j;
                if (v[j] > bv) { bv = v[j]; bi = t; }
            }
            #pragma unroll
            for (int m = 32; m; m >>= 1) {
                double ov = __shfl_xor(bv, m); int oi = __shfl_xor(bi, m);
                if (ov > bv || (ov == bv && oi < bi)) { bv = ov; bi = oi; }
            }
            if (lane == 0) ssel[it] = bi;
            #pragma unroll
            for (int j = 0; j < 16; ++j) {
                int t = lane + 64 * j;
                if (t == bi) v[j] = -DBL_MAX;
            }
        }
    }
    __syncthreads();
    for (int i = tid; i < 32 * C_; i += 256) {
        int r = i / C_, c = i - r * C_;
        float v = (r < K_) ? text[ssel[r] * C_ + c] : 0.f;
        if (r < K_) agg[b * K_ * C_ + i] = v;
        unsigned u = __float_as_uint(v);
        float fh = __uint_as_float(u & 0xffff0000u);
        hiL[i] = (unsigned short)(u >> 16);
        loL[i] = bf_rne(v - fh);
    }
    __syncthreads();
    for (int i = tid; i < 24 * 256; i += 256) {
        int p = i >> 8, r = i & 255, f = r >> 6, ln = r & 63;
        int row = (f & 1) * 16 + (ln & 15);
        int col = p * 32 + (ln >> 4) * 8;
        const unsigned short* src = ((f < 2) ? hiL : loL) + row * C_ + col;
        *(s16x8*)(Epk + ((size_t)b * 6144 + i) * 8) = *(const s16x8*)src;
    }
}

// ---------------- K2: row-resident MFMA argmax (sequential feat reads) ----------------
// One 16-px tile per block: 16 FULL rows (48KB contiguous) staged via
// global_load_lds (4 streams of 12KB, ascending), rows padded to 3136B with
// source-side lane-XOR (slot ^ 2*(row&3)) so fragment ds_read_b128 is <=4-way.
// K split across 4 waves (6 phases each), LDS partial-reduce, wave-0 epilogue.
// 3 blocks/CU; inter-block overlap hides stage<->compute alternation.
__global__ __launch_bounds__(256, 3) void k2_argmax(const float* __restrict__ feat,
                                                    const unsigned short* __restrict__ Epk,
                                                    int* __restrict__ kidx,
                                                    int* __restrict__ cnt,
                                                    int* __restrict__ flagcnt,
                                                    int* __restrict__ flaglist) {
    __shared__ float rows[16 * ROWF];     // 50176 B; reused as reduce buffer
    __shared__ int scnt[K_];
    int tid = threadIdx.x, wid = tid >> 6, lane = tid & 63;
    if (tid < K_) scnt[tid] = 0;

    int bx = blockIdx.x;                  // 8192 blocks: 32 b x 256 tiles
    int b = bx >> 8, t16 = bx & 255;
    int n0 = t16 * 16;
    const float* fb = feat + ((size_t)b * N_ + n0) * C_;
    const unsigned short* Eb = Epk + (size_t)b * 6144 * 8;

    // ---- stage: wave w -> rows 4w..4w+3, each row = 3 x 1KB DMA, src lane-XOR'd ----
    #pragma unroll
    for (int r2 = 0; r2 < 4; ++r2) {
        int r = wid * 4 + r2;
        int sw = 2 * (r & 3);             // 16B-slot XOR key
        #pragma unroll
        for (int c = 0; c < 3; ++c) {
            const float* src = fb + (size_t)r * C_ + c * 256 + ((lane ^ sw) * 4);
            float* dst = &rows[r * ROWF + c * 256];   // wave-uniform; HW adds lane*16
            __builtin_amdgcn_global_load_lds((const __attribute__((address_space(1))) void*)src,
                                             (__attribute__((address_space(3))) void*)dst, 16, 0, 0);
        }
    }
    __syncthreads();                      // drains vmcnt; rows ready

    // ---- compute: wave w owns phases 6w..6w+5 (split-K partial acc) ----
    int g = lane >> 4, r = lane & 15;
    int X = 8 * (r & 3);                  // dword-index XOR (matches source swizzle)
    s16x8 Ah0, Ah1, Al0, Al1;
    auto LOADA = [&](int p) {
        const s16x8* ap = (const s16x8*)(Eb + (size_t)p * 256 * 8);
        Ah0 = ap[lane]; Ah1 = ap[64 + lane];
        Al0 = ap[128 + lane]; Al1 = ap[192 + lane];
    };
    auto CVT = [&](f32x4 a, f32x4 c, s16x8& H, s16x8& L) {
        float x[8] = { a.x, a.y, a.z, a.w, c.x, c.y, c.z, c.w };
        unsigned hu[8], lu[8];
        #pragma unroll
        for (int j = 0; j < 8; ++j) {
            unsigned u = __float_as_uint(x[j]);
            hu[j] = u >> 16;
            lu[j] = bf_rne(x[j] - __uint_as_float(u & 0xffff0000u));
        }
        i32x4 hv = { (int)(hu[0] | (hu[1] << 16)), (int)(hu[2] | (hu[3] << 16)),
                     (int)(hu[4] | (hu[5] << 16)), (int)(hu[6] | (hu[7] << 16)) };
        i32x4 lv = { (int)(lu[0] | (lu[1] << 16)), (int)(lu[2] | (lu[3] << 16)),
                     (int)(lu[4] | (lu[5] << 16)), (int)(lu[6] | (lu[7] << 16)) };
        H = __builtin_bit_cast(s16x8, hv);
        L = __builtin_bit_cast(s16x8, lv);
    };

    f32x4 acc0 = (f32x4)0.f, acc1 = (f32x4)0.f;
    #pragma unroll
    for (int q = 0; q < 6; ++q) {
        int p = wid * 6 + q;
        LOADA(p);
        int dd = (32 * p + 8 * g) ^ X;    // stays within the aligned-8 run
        f32x4 f0 = *(const f32x4*)&rows[ROWF * r + dd];
        f32x4 f1 = *(const f32x4*)&rows[ROWF * r + dd + 4];
        s16x8 Bh, Bl;
        CVT(f0, f1, Bh, Bl);
        acc0 = __builtin_amdgcn_mfma_f32_16x16x32_bf16(Ah0, Bh, acc0, 0, 0, 0);
        acc1 = __builtin_amdgcn_mfma_f32_16x16x32_bf16(Ah1, Bh, acc1, 0, 0, 0);
        acc0 = __builtin_amdgcn_mfma_f32_16x16x32_bf16(Ah0, Bl, acc0, 0, 0, 0);
        acc1 = __builtin_amdgcn_mfma_f32_16x16x32_bf16(Ah1, Bl, acc1, 0, 0, 0);
        acc0 = __builtin_amdgcn_mfma_f32_16x16x32_bf16(Al0, Bh, acc0, 0, 0, 0);
        acc1 = __builtin_amdgcn_mfma_f32_16x16x32_bf16(Al1, Bh, acc1, 0, 0, 0);
    }

    // ---- cross-wave reduce (overlay rows buffer) ----
    __syncthreads();                      // all ds_reads of rows done
    float* red = rows;
    int li = tid * 8;
    #pragma unroll
    for (int j = 0; j < 4; ++j) { red[li + j] = acc0[j]; red[li + 4 + j] = acc1[j]; }
    __syncthreads();
    if (wid == 0) {
        #pragma unroll
        for (int w = 1; w < 4; ++w) {
            int oi = (w * 64 + lane) * 8;
            #pragma unroll
            for (int j = 0; j < 4; ++j) { acc0[j] += red[oi + j]; acc1[j] += red[oi + 4 + j]; }
        }
        // epilogue: top-2 over k (C/D: col=lane&15=px, row-class=(lane>>4)*4+reg)
        int kb = g * 4;
        float m1 = acc0[0]; int i1 = kb; float m2 = -FLT_MAX;
        #pragma unroll
        for (int rr = 1; rr < 4; ++rr) {
            float v = acc0[rr];
            if (v > m1) { m2 = m1; m1 = v; i1 = kb + rr; }
            else if (v > m2) m2 = v;
        }
        if (g == 0) {                     // k-tile 1: only classes 16..19 valid
            #pragma unroll
            for (int rr = 0; rr < 4; ++rr) {
                float v = acc1[rr];
                if (v > m1) { m2 = m1; m1 = v; i1 = 16 + rr; }
                else if (v > m2) m2 = v;
            }
        }
        #pragma unroll
        for (int s = 16; s < 64; s <<= 1) {
            float om1 = __shfl_xor(m1, s); int oi1 = __shfl_xor(i1, s);
            float om2 = __shfl_xor(m2, s);
            if (om1 > m1 || (om1 == m1 && oi1 < i1)) { m2 = fmaxf(m1, om2); m1 = om1; i1 = oi1; }
            else { m2 = fmaxf(m2, om1); }
        }
        if (lane < 16) {
            int n = n0 + lane;
            kidx[b * N_ + n] = i1;
            atomicAdd(&scnt[i1], 1);
            if (m1 - m2 < GAP_TH) {
                int pos = atomicAdd(flagcnt, 1);
                if (pos < MAXF) flaglist[pos] = b * N_ + n;
            }
        }
    }
    __syncthreads();
    if (tid < K_ && scnt[tid]) atomicAdd(&cnt[b * K_ + tid], scnt[tid]);
}

// ---------------- K2.5: fp64 re-decision for knife-edge pixels ----------------
__global__ __launch_bounds__(256) void k25_refine(const float* __restrict__ feat,
                                                  const float* __restrict__ agg,
                                                  int* __restrict__ kidx,
                                                  int* __restrict__ cnt,
                                                  const int* __restrict__ flagcnt,
                                                  const int* __restrict__ flaglist) {
    int wid = threadIdx.x >> 6, lane = threadIdx.x & 63;
    int wg = blockIdx.x * 4 + wid;
    int nf = flagcnt[0]; if (nf > MAXF) nf = MAXF;
    for (int e = wg; e < nf; e += gridDim.x * 4) {
        int pix = flaglist[e];
        int b = pix >> 12;
        const float* fr = feat + (size_t)pix * C_;
        const float* ebase = agg + b * K_ * C_;
        double fd[12];
        #pragma unroll
        for (int j = 0; j < 12; ++j) fd[j] = (double)fr[lane + 64 * j];
        double best = -DBL_MAX; int bi = 0;
        for (int k = 0; k < K_; ++k) {
            const float* er = ebase + k * C_;
            double s = 0.0;
            #pragma unroll
            for (int j = 0; j < 12; ++j) s += fd[j] * (double)er[lane + 64 * j];
            #pragma unroll
            for (int m = 32; m; m >>= 1) s += __shfl_xor(s, m);
            if (s > best) { best = s; bi = k; }
        }
        if (lane == 0) {
            int old = kidx[pix];
            if (old != bi) {
                kidx[pix] = bi;
                atomicSub(&cnt[b * K_ + old], 1);
                atomicAdd(&cnt[b * K_ + bi], 1);
            }
        }
    }
}

// ---------------- K3s: pre-scale agg rows by 1/(cnt+1) ----------------
__global__ __launch_bounds__(256) void k3s_scale(const float* __restrict__ agg,
                                                 const int* __restrict__ cnt,
                                                 float* __restrict__ sagg) {
    __shared__ float sc[K_];
    int b = blockIdx.x, tid = threadIdx.x;
    if (tid < K_) sc[tid] = 1.0f / ((float)cnt[b * K_ + tid] + 1.0f);  // IEEE div, matches ref
    __syncthreads();
    const f32x4* a4 = (const f32x4*)(agg + (size_t)b * K_ * C_);
    f32x4* s4 = (f32x4*)(sagg + (size_t)b * K_ * C_);
    #pragma unroll 1
    for (int i = tid; i < K_ * (C_ / 4); i += 256) {
        int k = i / (C_ / 4);
        s4[i] = a4[i] * sc[k];
    }
}

// ---------------- K4: gather+store only (8 px/wave, 2-deep pipeline) ----------------
__global__ __launch_bounds__(256) void k4_out(const float* __restrict__ sagg,
                                              const int* __restrict__ kidx,
                                              float* __restrict__ out) {
    int wid = threadIdx.x >> 6, lane = threadIdx.x & 63;
    int wg = blockIdx.x * 4 + wid;          // 16384 waves, 8 px each
    int base = wg * 8;
    int b = base >> 12;                     // wave-uniform (8 | 4096)
    int kk[8];
    #pragma unroll
    for (int i = 0; i < 8; ++i) kk[i] = kidx[base + i];
    const f32x4* sagg4 = (const f32x4*)sagg;
    f32x4* out4 = (f32x4*)out;

    f32x4 va0, va1, va2, vb0, vb1, vb2;
    {
        const f32x4* a4 = sagg4 + (size_t)(b * K_ + kk[0]) * (C_ / 4);
        va0 = a4[lane]; va1 = a4[lane + 64]; va2 = a4[lane + 128];
    }
    #pragma unroll
    for (int i = 0; i < 8; ++i) {
        if (i + 1 < 8) {
            const f32x4* a4 = sagg4 + (size_t)(b * K_ + kk[i + 1]) * (C_ / 4);
            vb0 = a4[lane]; vb1 = a4[lane + 64]; vb2 = a4[lane + 128];
        }
        f32x4* o4 = out4 + (size_t)(base + i) * (C_ / 4);
        o4[lane] = va0; o4[lane + 64] = va1; o4[lane + 128] = va2;
        va0 = vb0; va1 = vb1; va2 = vb2;
    }
}

extern "C" void kernel_launch(void* const* d_in, const int* in_sizes, int n_in,
                              void* d_out, int out_size, void* d_ws, size_t ws_size,
                              hipStream_t stream) {
    const float* g_feat = (const float*)d_in[0];
    const float* feat   = (const float*)d_in[1];
    // d_in[2] = tau: positive scale, numerically irrelevant (attn == y_hard exactly)
    const float* text   = (const float*)d_in[3];
    float* out = (float*)d_out;

    char* ws = (char*)d_ws;
    double* logits        = (double*)(ws + 0);         // 256000 B
    float*  agg           = (float*) (ws + 262144);    // 1966080 B
    int*    cnt           = (int*)   (ws + 2230784);   // 2560 B
    int*    flagc         = (int*)   (ws + 2233344);   // 64 B
    int*    flagl         = (int*)   (ws + 2233408);   // 65536 B
    int*    kidx          = (int*)   (ws + 2301504);   // 524288 B
    unsigned short* Epk   = (unsigned short*)(ws + 2825792);  // 3145728 B
    float*  sagg          = (float*) (ws + 5971520);   // 1966080 B

    k1_logits<<<dim3(32, 250), 256, 0, stream>>>(g_feat, text, logits, cnt, flagc);
    k1b_topk<<<32, 256, 0, stream>>>(logits, text, agg, Epk);
    k2_argmax<<<8192, 256, 0, stream>>>(feat, Epk, kidx, cnt, flagc, flagl);
    k25_refine<<<1024, 256, 0, stream>>>(feat, agg, kidx, cnt, flagc, flagl);
    k3s_scale<<<32, 256, 0, stream>>>(agg, cnt, sagg);
    k4_out<<<4096, 256, 0, stream>>>(sagg, kidx, out);
}

// Round 17
// 265.761 us; speedup vs baseline: 1.2849x; 1.0337x over previous
//
#include <hip/hip_runtime.h>
#include <cfloat>

#define B_ 32
#define N_ 4096
#define C_ 768
#define T_ 1000
#define K_ 20

#define PHC 32            // floats per c-phase (one MFMA K=32 step)
#define NPH (C_/PHC)      // 24 phases
#define SPP 4             // phases per super-phase (512B row bursts)
#define NSP (NPH/SPP)     // 6 super-phases
#define GAP_TH 1e-4f
#define MAXF 16384

typedef float f32x4 __attribute__((ext_vector_type(4)));
typedef int   i32x4 __attribute__((ext_vector_type(4)));
typedef short s16x8 __attribute__((ext_vector_type(8)));   // 8 bf16 (4 VGPR)

__device__ __forceinline__ unsigned short bf_rne(float x) {
    unsigned u = __float_as_uint(x);
    return (unsigned short)((u + 0x7fffu + ((u >> 16) & 1u)) >> 16);
}

// ---------------- K1a: vg_logit in fp64 (+ zero counters) ----------------
__global__ __launch_bounds__(256) void k1_logits(const float* __restrict__ g_feat,
                                                 const float* __restrict__ text,
                                                 double* __restrict__ logits,
                                                 int* __restrict__ cnt,
                                                 int* __restrict__ flagcnt) {
    int b = blockIdx.x;
    int wid = threadIdx.x >> 6, lane = threadIdx.x & 63;
    int t = blockIdx.y * 4 + wid;           // grid.y = 250 -> t in [0,1000)
    if (b == 0 && blockIdx.y == 0) {
        for (int i = threadIdx.x; i < B_ * K_; i += 256) cnt[i] = 0;
        if (threadIdx.x == 0) flagcnt[0] = 0;
    }
    const float* g = g_feat + b * C_;
    const float* e = text + t * C_;
    double s = 0.0;
    #pragma unroll
    for (int j = 0; j < 12; ++j) {
        int c = lane + 64 * j;
        s += (double)g[c] * (double)e[c];
    }
    #pragma unroll
    for (int m = 32; m; m >>= 1) s += __shfl_xor(s, m);
    if (lane == 0) logits[b * T_ + t] = s;
}

// ---------------- K1b: top-20 + gather + A-fragment-ordered bf16 hi/lo pack ----------------
__global__ __launch_bounds__(256) void k1b_topk(const double* __restrict__ logits,
                                                const float* __restrict__ text,
                                                float* __restrict__ agg,
                                                unsigned short* __restrict__ Epk) {
    __shared__ unsigned short hiL[32 * C_];   // 48 KB
    __shared__ unsigned short loL[32 * C_];   // 48 KB
    __shared__ int ssel[K_];
    int b = blockIdx.x, tid = threadIdx.x, lane = tid & 63;
    if (tid < 64) {
        double v[16];
        #pragma unroll
        for (int j = 0; j < 16; ++j) {
            int t = lane + 64 * j;
            v[j] = (t < T_) ? logits[b * T_ + t] : -DBL_MAX;
        }
        for (int it = 0; it < K_; ++it) {
            double bv = -DBL_MAX; int bi = 0x7fffffff;
            #pragma unroll
            for (int j = 0; j < 16; ++j) {
                int t = lane + 64 * j;
                if (v[j] > bv) { bv = v[j]; bi = t; }
            }
            #pragma unroll
            for (int m = 32; m; m >>= 1) {
                double ov = __shfl_xor(bv, m); int oi = __shfl_xor(bi, m);
                if (ov > bv || (ov == bv && oi < bi)) { bv = ov; bi = oi; }
            }
            if (lane == 0) ssel[it] = bi;
            #pragma unroll
            for (int j = 0; j < 16; ++j) {
                int t = lane + 64 * j;
                if (t == bi) v[j] = -DBL_MAX;
            }
        }
    }
    __syncthreads();
    for (int i = tid; i < 32 * C_; i += 256) {
        int r = i / C_, c = i - r * C_;
        float v = (r < K_) ? text[ssel[r] * C_ + c] : 0.f;
        if (r < K_) agg[b * K_ * C_ + i] = v;
        unsigned u = __float_as_uint(v);
        float fh = __uint_as_float(u & 0xffff0000u);
        hiL[i] = (unsigned short)(u >> 16);
        loL[i] = bf_rne(v - fh);
    }
    __syncthreads();
    for (int i = tid; i < 24 * 256; i += 256) {
        int p = i >> 8, r = i & 255, f = r >> 6, ln = r & 63;
        int row = (f & 1) * 16 + (ln & 15);
        int col = p * 32 + (ln >> 4) * 8;
        const unsigned short* src = ((f < 2) ? hiL : loL) + row * C_ + col;
        *(s16x8*)(Epk + ((size_t)b * 6144 + i) * 8) = *(const s16x8*)src;
    }
}

// ---------------- K2: LDS-free MFMA argmax, NON-TEMPORAL feat reads ----------------
// R17 single-variable test: cold feat reads cap at ~2.4 TB/s regardless of
// pattern (R13-R16), while L3-warm consumption runs 6+ TB/s (R15 probe).
// Theory: read misses are throttled by Infinity-Cache FILL allocation, not
// HBM. __builtin_nontemporal_load (nt policy) on feat should bypass L3
// allocation and lift the cold read rate. Epk loads keep normal caching.
__global__ __launch_bounds__(256, 4) void k2_argmax(const float* __restrict__ feat,
                                                    const unsigned short* __restrict__ Epk,
                                                    int* __restrict__ kidx,
                                                    int* __restrict__ cnt,
                                                    int* __restrict__ flagcnt,
                                                    int* __restrict__ flaglist) {
    __shared__ int scnt[K_];
    int tid = threadIdx.x, wid = tid >> 6, lane = tid & 63;
    if (tid < K_) scnt[tid] = 0;
    __syncthreads();

    int gw = blockIdx.x * 4 + wid;           // global wave 0..8191
    int b  = gw >> 8;                        // 256 waves per batch
    int n0 = (gw & 255) * 16;                // pixel base within batch
    int prow = lane & 15;                    // my pixel within the tile
    int g    = lane >> 4;                    // my k-group (0..3)
    const float* fp0 = feat + ((size_t)b * N_ + n0 + prow) * C_ + g * 8;
    const unsigned short* Eb = Epk + (size_t)b * 6144 * 8;

    f32x4 fA[2 * SPP], fB[2 * SPP];
    auto LOADSP = [&](int sp, f32x4* fr) {
        #pragma unroll
        for (int q = 0; q < SPP; ++q) {       // ascending addresses: 512B/row burst
            fr[2 * q]     = __builtin_nontemporal_load((const f32x4*)(fp0 + (sp * SPP + q) * PHC));
            fr[2 * q + 1] = __builtin_nontemporal_load((const f32x4*)(fp0 + (sp * SPP + q) * PHC + 4));
        }
    };

    s16x8 Ah0, Ah1, Al0, Al1;
    auto LOADA = [&](int p) {
        const s16x8* ap = (const s16x8*)(Eb + (size_t)p * 256 * 8);
        Ah0 = ap[lane]; Ah1 = ap[64 + lane];
        Al0 = ap[128 + lane]; Al1 = ap[192 + lane];
    };
    auto CVT = [&](f32x4 a, f32x4 c, s16x8& H, s16x8& L) {
        float x[8] = { a.x, a.y, a.z, a.w, c.x, c.y, c.z, c.w };
        unsigned hu[8], lu[8];
        #pragma unroll
        for (int j = 0; j < 8; ++j) {
            unsigned u = __float_as_uint(x[j]);
            hu[j] = u >> 16;
            lu[j] = bf_rne(x[j] - __uint_as_float(u & 0xffff0000u));
        }
        i32x4 hv = { (int)(hu[0] | (hu[1] << 16)), (int)(hu[2] | (hu[3] << 16)),
                     (int)(hu[4] | (hu[5] << 16)), (int)(hu[6] | (hu[7] << 16)) };
        i32x4 lv = { (int)(lu[0] | (lu[1] << 16)), (int)(lu[2] | (lu[3] << 16)),
                     (int)(lu[4] | (lu[5] << 16)), (int)(lu[6] | (lu[7] << 16)) };
        H = __builtin_bit_cast(s16x8, hv);
        L = __builtin_bit_cast(s16x8, lv);
    };

    f32x4 acc0 = (f32x4)0.f, acc1 = (f32x4)0.f;
    LOADSP(0, fA);

    #pragma unroll 1
    for (int sp = 0; sp < NSP; ++sp) {
        f32x4* cur = (sp & 1) ? fB : fA;
        f32x4* nxt = (sp & 1) ? fA : fB;
        if (sp + 1 < NSP) LOADSP(sp + 1, nxt);   // in flight through 4 phases
        #pragma unroll
        for (int q = 0; q < SPP; ++q) {
            LOADA(sp * SPP + q);                  // 4 L2-hot 1KB wave-loads
            s16x8 Bh, Bl;
            CVT(cur[2 * q], cur[2 * q + 1], Bh, Bl);
            acc0 = __builtin_amdgcn_mfma_f32_16x16x32_bf16(Ah0, Bh, acc0, 0, 0, 0);
            acc1 = __builtin_amdgcn_mfma_f32_16x16x32_bf16(Ah1, Bh, acc1, 0, 0, 0);
            acc0 = __builtin_amdgcn_mfma_f32_16x16x32_bf16(Ah0, Bl, acc0, 0, 0, 0);
            acc1 = __builtin_amdgcn_mfma_f32_16x16x32_bf16(Ah1, Bl, acc1, 0, 0, 0);
            acc0 = __builtin_amdgcn_mfma_f32_16x16x32_bf16(Al0, Bh, acc0, 0, 0, 0);
            acc1 = __builtin_amdgcn_mfma_f32_16x16x32_bf16(Al1, Bh, acc1, 0, 0, 0);
        }
    }

    // epilogue: top-2 over k (C/D: col=lane&15=px, row-class=(lane>>4)*4+reg)
    int kb = g * 4;
    float m1 = acc0[0]; int i1 = kb; float m2 = -FLT_MAX;
    #pragma unroll
    for (int r = 1; r < 4; ++r) {
        float v = acc0[r];
        if (v > m1) { m2 = m1; m1 = v; i1 = kb + r; }
        else if (v > m2) m2 = v;
    }
    if (g == 0) {                            // k-tile 1: only classes 16..19 valid
        #pragma unroll
        for (int r = 0; r < 4; ++r) {
            float v = acc1[r];
            if (v > m1) { m2 = m1; m1 = v; i1 = 16 + r; }
            else if (v > m2) m2 = v;
        }
    }
    #pragma unroll
    for (int s = 16; s < 64; s <<= 1) {
        float om1 = __shfl_xor(m1, s); int oi1 = __shfl_xor(i1, s);
        float om2 = __shfl_xor(m2, s);
        if (om1 > m1 || (om1 == m1 && oi1 < i1)) { m2 = fmaxf(m1, om2); m1 = om1; i1 = oi1; }
        else { m2 = fmaxf(m2, om1); }
    }
    if (lane < 16) {
        int n = n0 + lane;
        kidx[b * N_ + n] = i1;
        atomicAdd(&scnt[i1], 1);
        if (m1 - m2 < GAP_TH) {
            int pos = atomicAdd(flagcnt, 1);
            if (pos < MAXF) flaglist[pos] = b * N_ + n;
        }
    }
    __syncthreads();
    if (tid < K_) atomicAdd(&cnt[b * K_ + tid], scnt[tid]);
}

// ---------------- K2.5: fp64 re-decision for knife-edge pixels ----------------
__global__ __launch_bounds__(256) void k25_refine(const float* __restrict__ feat,
                                                  const float* __restrict__ agg,
                                                  int* __restrict__ kidx,
                                                  int* __restrict__ cnt,
                                                  const int* __restrict__ flagcnt,
                                                  const int* __restrict__ flaglist) {
    int wid = threadIdx.x >> 6, lane = threadIdx.x & 63;
    int wg = blockIdx.x * 4 + wid;
    int nf = flagcnt[0]; if (nf > MAXF) nf = MAXF;
    for (int e = wg; e < nf; e += gridDim.x * 4) {
        int pix = flaglist[e];
        int b = pix >> 12;
        const float* fr = feat + (size_t)pix * C_;
        const float* ebase = agg + b * K_ * C_;
        double fd[12];
        #pragma unroll
        for (int j = 0; j < 12; ++j) fd[j] = (double)fr[lane + 64 * j];
        double best = -DBL_MAX; int bi = 0;
        for (int k = 0; k < K_; ++k) {
            const float* er = ebase + k * C_;
            double s = 0.0;
            #pragma unroll
            for (int j = 0; j < 12; ++j) s += fd[j] * (double)er[lane + 64 * j];
            #pragma unroll
            for (int m = 32; m; m >>= 1) s += __shfl_xor(s, m);
            if (s > best) { best = s; bi = k; }
        }
        if (lane == 0) {
            int old = kidx[pix];
            if (old != bi) {
                kidx[pix] = bi;
                atomicSub(&cnt[b * K_ + old], 1);
                atomicAdd(&cnt[b * K_ + bi], 1);
            }
        }
    }
}

// ---------------- K3s: pre-scale agg rows by 1/(cnt+1) ----------------
__global__ __launch_bounds__(256) void k3s_scale(const float* __restrict__ agg,
                                                 const int* __restrict__ cnt,
                                                 float* __restrict__ sagg) {
    __shared__ float sc[K_];
    int b = blockIdx.x, tid = threadIdx.x;
    if (tid < K_) sc[tid] = 1.0f / ((float)cnt[b * K_ + tid] + 1.0f);  // IEEE div, matches ref
    __syncthreads();
    const f32x4* a4 = (const f32x4*)(agg + (size_t)b * K_ * C_);
    f32x4* s4 = (f32x4*)(sagg + (size_t)b * K_ * C_);
    #pragma unroll 1
    for (int i = tid; i < K_ * (C_ / 4); i += 256) {
        int k = i / (C_ / 4);
        s4[i] = a4[i] * sc[k];
    }
}

// ---------------- K4: gather+store only (8 px/wave, 2-deep pipeline) ----------------
__global__ __launch_bounds__(256) void k4_out(const float* __restrict__ sagg,
                                              const int* __restrict__ kidx,
                                              float* __restrict__ out) {
    int wid = threadIdx.x >> 6, lane = threadIdx.x & 63;
    int wg = blockIdx.x * 4 + wid;          // 16384 waves, 8 px each
    int base = wg * 8;
    int b = base >> 12;                     // wave-uniform (8 | 4096)
    int kk[8];
    #pragma unroll
    for (int i = 0; i < 8; ++i) kk[i] = kidx[base + i];
    const f32x4* sagg4 = (const f32x4*)sagg;
    f32x4* out4 = (f32x4*)out;

    f32x4 va0, va1, va2, vb0, vb1, vb2;
    {
        const f32x4* a4 = sagg4 + (size_t)(b * K_ + kk[0]) * (C_ / 4);
        va0 = a4[lane]; va1 = a4[lane + 64]; va2 = a4[lane + 128];
    }
    #pragma unroll
    for (int i = 0; i < 8; ++i) {
        if (i + 1 < 8) {
            const f32x4* a4 = sagg4 + (size_t)(b * K_ + kk[i + 1]) * (C_ / 4);
            vb0 = a4[lane]; vb1 = a4[lane + 64]; vb2 = a4[lane + 128];
        }
        f32x4* o4 = out4 + (size_t)(base + i) * (C_ / 4);
        o4[lane] = va0; o4[lane + 64] = va1; o4[lane + 128] = va2;
        va0 = vb0; va1 = vb1; va2 = vb2;
    }
}

extern "C" void kernel_launch(void* const* d_in, const int* in_sizes, int n_in,
                              void* d_out, int out_size, void* d_ws, size_t ws_size,
                              hipStream_t stream) {
    const float* g_feat = (const float*)d_in[0];
    const float* feat   = (const float*)d_in[1];
    // d_in[2] = tau: positive scale, numerically irrelevant (attn == y_hard exactly)
    const float* text   = (const float*)d_in[3];
    float* out = (float*)d_out;

    char* ws = (char*)d_ws;
    double* logits        = (double*)(ws + 0);         // 256000 B
    float*  agg           = (float*) (ws + 262144);    // 1966080 B
    int*    cnt           = (int*)   (ws + 2230784);   // 2560 B
    int*    flagc         = (int*)   (ws + 2233344);   // 64 B
    int*    flagl         = (int*)   (ws + 2233408);   // 65536 B
    int*    kidx          = (int*)   (ws + 2301504);   // 524288 B
    unsigned short* Epk   = (unsigned short*)(ws + 2825792);  // 3145728 B
    float*  sagg          = (float*) (ws + 5971520);   // 1966080 B

    k1_logits<<<dim3(32, 250), 256, 0, stream>>>(g_feat, text, logits, cnt, flagc);
    k1b_topk<<<32, 256, 0, stream>>>(logits, text, agg, Epk);
    k2_argmax<<<2048, 256, 0, stream>>>(feat, Epk, kidx, cnt, flagc, flagl);
    k25_refine<<<1024, 256, 0, stream>>>(feat, agg, kidx, cnt, flagc, flagl);
    k3s_scale<<<32, 256, 0, stream>>>(agg, cnt, sagg);
    k4_out<<<4096, 256, 0, stream>>>(sagg, kidx, out);
}